// Round 7
// baseline (571.824 us; speedup 1.0000x reference)
//
#include <hip/hip_runtime.h>
#include <hip/hip_bf16.h>

// QuantizedLayer: W[4096,4096] decoded from 3-bit packed codes (8-entry codebook),
// X[8192,4096] f32, out = X @ W^T + bias, f32 out. bf16 MFMA path (threshold 8.4).
//
// Decode semantics (established R0/R4/R6 evidence): codes buffer is int32
// (JAX x64 off in the generator; POWERS downcast-wrapped: 8^s -> 0 for s>=11).
// Reference ran under XLA: floor_divide(c, 0) = -2 (safe-div -1, safe-rem c,
// floor-adjust), so idx = (-2) % 8 = 6 for all s>=11 (7 iff c==0).
// s<=10: true floor-div == arithmetic shift of sign-extended word.
#define OUT_DIM 4096
#define IN_DIM  4096
#define NUMEL   (OUT_DIM * IN_DIM)   // 16777216
#define NCODES  798916

typedef __bf16 bf16x8 __attribute__((ext_vector_type(8)));
typedef float  f32x4  __attribute__((ext_vector_type(4)));
typedef unsigned short u16;
typedef unsigned long long u64;
typedef long long s64;

// round-to-nearest-even f32 -> bf16 bits
__device__ inline u16 f2bf(float f) {
    union { float f; unsigned u; } v; v.f = f;
    unsigned u = v.u;
    return (u16)((u + 0x7fffu + ((u >> 16) & 1u)) >> 16);
}

// ---- dtype probe: true iff codes buffer holds int64 words (defensive; evidence
// says i32). For true int64 codes every high word is >=0; for int32 codes odd
// words have random sign (P(all 64 nonneg) ~ 2^-64). Reads 512B -> safe.
__device__ __forceinline__ bool codes_are_i64(const int* c32) {
    int lane = threadIdx.x & 63;
    int w = c32[2 * lane + 1];
    return __all(w >= 0) != 0;
}

// Pack 8 bf16 centroids into two u64 registers (no LDS, no indexed array).
__device__ __forceinline__ void make_lut(const float* centroids, u64& lut0, u64& lut1) {
    lut0 = 0; lut1 = 0;
    #pragma unroll
    for (int i = 0; i < 4; i++) lut0 |= (u64)f2bf(centroids[i])     << (16 * i);
    #pragma unroll
    for (int i = 0; i < 4; i++) lut1 |= (u64)f2bf(centroids[4 + i]) << (16 * i);
}

// Decode 8 consecutive weights at flat position pbase (pbase < 2^24).
__device__ __forceinline__ uint4 decode8(const void* codes, bool i64,
                                         u64 lut0, u64 lut1, unsigned pbase) {
    // q = pbase/21 exact for pbase < 2^24 (magic ceil(2^36/21))
    unsigned q0 = (unsigned)(((u64)pbase * 0xC30C30C4ULL) >> 36);
    unsigned s0 = pbase - q0 * 21u;
    unsigned q1 = q0 + 1u; if (q1 > (unsigned)(NCODES - 1)) q1 = (unsigned)(NCODES - 1);
    s64 w0, w1;
    if (i64) {
        w0 = ((const s64*)codes)[q0];
        w1 = ((const s64*)codes)[q1];
    } else {
        w0 = (s64)((const int*)codes)[q0];   // sign-extend int32 word
        w1 = (s64)((const int*)codes)[q1];
    }
    unsigned r[4];
    #pragma unroll
    for (int i = 0; i < 8; i++) {
        unsigned s  = s0 + (unsigned)i;
        s64 w       = (s >= 21u) ? w1 : w0;
        unsigned ss = (s >= 21u) ? (s - 21u) : s;
        unsigned idx;
        if (i64) {
            idx = (unsigned)(w >> (3u * ss)) & 7u;          // true int64 unpack
        } else {
            if (ss <= 10u) idx = (unsigned)(w >> (3u * ss)) & 7u;  // exact floor-div
            else           idx = (w == 0) ? 7u : 6u;        // XLA //0 -> -2 -> %8 = 6
        }
        u64 pk = (idx & 4u) ? lut1 : lut0;
        unsigned val = (unsigned)(pk >> (16u * (idx & 3u))) & 0xFFFFu;
        if (i & 1) r[i >> 1] |= val << 16; else r[i >> 1] = val;
    }
    return make_uint4(r[0], r[1], r[2], r[3]);
}

// ---------------- kernel 1: decode packed codes -> bf16 weight (paths A/B) ----
__global__ __launch_bounds__(256) void decode_codes_vec(
    const void* __restrict__ codes, const float* __restrict__ centroids,
    uint4* __restrict__ W)
{
    bool i64 = codes_are_i64((const int*)codes);
    u64 lut0, lut1; make_lut(centroids, lut0, lut1);
    unsigned c = blockIdx.x * blockDim.x + threadIdx.x;   // 16B chunk id
    if (c >= NUMEL / 8) return;
    W[c] = decode8(codes, i64, lut0, lut1, c * 8u);
}

// ---------------- kernel 2: X f32 -> bf16 (path A) ----------------
__global__ void f32_to_bf16_vec(const float4* __restrict__ x,
                                ushort4* __restrict__ y, int n4) {
    int stride = gridDim.x * blockDim.x;
    for (int i = blockIdx.x * blockDim.x + threadIdx.x; i < n4; i += stride) {
        float4 v = x[i];
        ushort4 o;
        o.x = f2bf(v.x); o.y = f2bf(v.y); o.z = f2bf(v.z); o.w = f2bf(v.w);
        y[i] = o;
    }
}

// ---------------- kernel 3: bf16 GEMM (B^T) + bias, f32 out ----------------
// m97 structure: 128x128 tile, BK=32, 4 waves x (4x4 of 16x16x32 MFMA).
// CONV_A: A is f32, convert during reg-staged LDS write (else bf16 via GLDS).
// FUSE_B: B decoded from codes during staging (else bf16 W via GLDS).
#define BM 128
#define BN 128
#define BK 32

#define GLDS(gaddr, laddr) \
    __builtin_amdgcn_global_load_lds( \
        (const __attribute__((address_space(1))) void*)(gaddr), \
        (__attribute__((address_space(3))) void*)(laddr), 16, 0, 0)

template<bool CONV_A, bool FUSE_B>
__global__ __launch_bounds__(256) void gemm_bt_bias(
    const void* __restrict__ Araw, const void* __restrict__ Braw,
    const float* __restrict__ centroids,
    const float* __restrict__ bias, float* __restrict__ C,
    int M, int N, int K)
{
    __shared__ u16 As[BM * BK];   // 8 KB linear row*BK+col; elem 8*t == 16B chunk t
    __shared__ u16 Bs[BN * BK];

    const int tid  = threadIdx.x;
    const int lane = tid & 63;
    const int wid  = tid >> 6;
    const int wm   = wid >> 1;
    const int wn   = wid & 1;

    const int bm = blockIdx.y * BM;
    const int bn = blockIdx.x * BN;

    bool i64f = false; u64 lut0 = 0, lut1 = 0;
    if constexpr (FUSE_B) {
        i64f = codes_are_i64((const int*)Braw);
        make_lut(centroids, lut0, lut1);
    }

    f32x4 acc[4][4] = {};

    // 16B-chunk staging map: chunk t -> row t>>2 (+64 second half), k-sub (t&3)*8
    const int r0  = tid >> 2;
    const int cs8 = (tid & 3) * 8;

    const u16*   gB0 = nullptr; const u16*   gB1 = nullptr;
    if constexpr (!FUSE_B) {
        const u16* Bb = (const u16*)Braw;
        gB0 = Bb + (long long)(bn + r0)      * K + cs8;
        gB1 = Bb + (long long)(bn + r0 + 64) * K + cs8;
    }
    const u16*   gA0 = nullptr; const u16*   gA1 = nullptr;
    const float* fA0 = nullptr; const float* fA1 = nullptr;
    if constexpr (CONV_A) {
        const float* Af = (const float*)Araw;
        fA0 = Af + (long long)(bm + r0)      * K + cs8;
        fA1 = Af + (long long)(bm + r0 + 64) * K + cs8;
    } else {
        const u16* Ab = (const u16*)Araw;
        gA0 = Ab + (long long)(bm + r0)      * K + cs8;
        gA1 = Ab + (long long)(bm + r0 + 64) * K + cs8;
    }

    // MFMA 16x16x32 fragment coords: lane -> row lane&15, k = (lane>>4)*8
    const int fr = lane & 15;
    const int fk = (lane >> 4) * 8;

    for (int kt = 0; kt < K; kt += BK) {
        // ---- B staging ----
        if constexpr (FUSE_B) {
            uint4 b0 = decode8(Braw, i64f, lut0, lut1,
                               (unsigned)((bn + r0) * K + kt + cs8));
            uint4 b1 = decode8(Braw, i64f, lut0, lut1,
                               (unsigned)((bn + r0 + 64) * K + kt + cs8));
            *(uint4*)&Bs[tid * 8]        = b0;   // ds_write_b128, linear
            *(uint4*)&Bs[2048 + tid * 8] = b1;
        } else {
            GLDS(gB0 + kt, &Bs[tid * 8]);
            GLDS(gB1 + kt, &Bs[2048 + tid * 8]);
        }
        // ---- A staging ----
        if constexpr (CONV_A) {
            f32x4 v0 = *(const f32x4*)(fA0 + kt);
            f32x4 v1 = *(const f32x4*)(fA0 + kt + 4);
            f32x4 v2 = *(const f32x4*)(fA1 + kt);
            f32x4 v3 = *(const f32x4*)(fA1 + kt + 4);
            bf16x8 a0, a1;
            #pragma unroll
            for (int i = 0; i < 4; i++) {
                a0[i]     = (__bf16)v0[i];
                a0[i + 4] = (__bf16)v1[i];
                a1[i]     = (__bf16)v2[i];
                a1[i + 4] = (__bf16)v3[i];
            }
            *(bf16x8*)&As[tid * 8]        = a0;
            *(bf16x8*)&As[2048 + tid * 8] = a1;
        } else {
            GLDS(gA0 + kt, &As[tid * 8]);
            GLDS(gA1 + kt, &As[2048 + tid * 8]);
        }
        __syncthreads();   // compiler drains vmcnt+lgkmcnt before barrier

        bf16x8 a[4], b[4];
        #pragma unroll
        for (int i = 0; i < 4; i++) {
            a[i] = *(const bf16x8*)&As[(wm * 64 + i * 16 + fr) * BK + fk];
            b[i] = *(const bf16x8*)&Bs[(wn * 64 + i * 16 + fr) * BK + fk];
        }
        #pragma unroll
        for (int i = 0; i < 4; i++)
            #pragma unroll
            for (int j = 0; j < 4; j++)
                acc[i][j] = __builtin_amdgcn_mfma_f32_16x16x32_bf16(
                    a[i], b[j], acc[i][j], 0, 0, 0);
        __syncthreads();
    }

    // Epilogue: D mapping col=lane&15, row=(lane>>4)*4+reg (m89/m91 verified)
    const int cr = (lane >> 4) * 4;
    const int cc = lane & 15;
    #pragma unroll
    for (int i = 0; i < 4; i++) {
        int row = bm + wm * 64 + i * 16 + cr;
        #pragma unroll
        for (int j = 0; j < 4; j++) {
            int col = bn + wn * 64 + j * 16 + cc;
            float bv = bias[col];
            #pragma unroll
            for (int r = 0; r < 4; r++) {
                C[(long long)(row + r) * N + col] = acc[i][j][r] + bv;
            }
        }
    }
}

extern "C" void kernel_launch(void* const* d_in, const int* in_sizes, int n_in,
                              void* d_out, int out_size, void* d_ws, size_t ws_size,
                              hipStream_t stream) {
    const float* input_    = (const float*)d_in[0];   // [4,2048,4096] f32
    const void*  codes     = d_in[1];                 // [798916] i32 (probed, i64 fallback)
    const float* centroids = (const float*)d_in[2];   // [8] f32
    const float* bias      = (const float*)d_in[3];   // [4096] f32
    float*       out       = (float*)d_out;           // [8192,4096] f32

    const int M = in_sizes[0] / IN_DIM;               // 8192

    const size_t needW = (size_t)NUMEL * 2;                 // 33.5 MB
    const size_t needX = (size_t)M * IN_DIM * 2;            // 67 MB

    dim3 grid(OUT_DIM / BN, M / BM);   // (32, 64)

    if (ws_size >= needW + needX) {
        // Path A: decode W + pre-convert X, full GLDS staging
        u16* W = (u16*)d_ws;
        u16* X = (u16*)((char*)d_ws + needW);
        decode_codes_vec<<<(NUMEL / 8) / 256, 256, 0, stream>>>(codes, centroids, (uint4*)W);
        int n4 = (M * IN_DIM) / 4;
        f32_to_bf16_vec<<<2048, 256, 0, stream>>>((const float4*)input_, (ushort4*)X, n4);
        gemm_bt_bias<false, false><<<grid, 256, 0, stream>>>(
            X, W, centroids, bias, out, M, OUT_DIM, IN_DIM);
    } else if (ws_size >= needW) {
        // Path B: decode W; GEMM converts f32 A on the fly
        u16* W = (u16*)d_ws;
        decode_codes_vec<<<(NUMEL / 8) / 256, 256, 0, stream>>>(codes, centroids, (uint4*)W);
        gemm_bt_bias<true, false><<<grid, 256, 0, stream>>>(
            input_, W, centroids, bias, out, M, OUT_DIM, IN_DIM);
    } else {
        // Path C: zero-scratch — decode B and convert A inside the GEMM
        gemm_bt_bias<true, true><<<grid, 256, 0, stream>>>(
            input_, codes, centroids, bias, out, M, OUT_DIM, IN_DIM);
    }
}

// Round 8
// 478.936 us; speedup vs baseline: 1.1939x; 1.1939x over previous
//
#include <hip/hip_runtime.h>
#include <hip/hip_bf16.h>

// QuantizedLayer: W[4096,4096] decoded from 3-bit packed codes (8-entry codebook),
// X[8192,4096] f32, out = X @ W^T + bias, f32 out. bf16 MFMA path (threshold 8.4).
//
// Decode semantics (R0/R4/R6/R7 evidence, R7 PASSED absmax=2.0): codes buffer is
// int32 (JAX x64 off; POWERS wrapped: 8^s==0 for s>=11). XLA floor_divide(c,0) = -2
// -> idx = 6 for s>=11 (7 iff c==0). s<=10: arithmetic shift of sign-extended word.
#define OUT_DIM 4096
#define IN_DIM  4096
#define NUMEL   (OUT_DIM * IN_DIM)   // 16777216
#define NCODES  798916

typedef __bf16 bf16x8 __attribute__((ext_vector_type(8)));
typedef float  f32x4  __attribute__((ext_vector_type(4)));
typedef unsigned short u16;
typedef unsigned long long u64;
typedef long long s64;

// round-to-nearest-even f32 -> bf16 bits
__device__ inline u16 f2bf(float f) {
    union { float f; unsigned u; } v; v.f = f;
    unsigned u = v.u;
    return (u16)((u + 0x7fffu + ((u >> 16) & 1u)) >> 16);
}

// ---- dtype probe (defensive; R7 evidence says i32) ----
__device__ __forceinline__ bool codes_are_i64(const int* c32) {
    int lane = threadIdx.x & 63;
    int w = c32[2 * lane + 1];
    return __all(w >= 0) != 0;
}

// Pack 8 bf16 centroids into two u64 registers.
__device__ __forceinline__ void make_lut(const float* centroids, u64& lut0, u64& lut1) {
    lut0 = 0; lut1 = 0;
    #pragma unroll
    for (int i = 0; i < 4; i++) lut0 |= (u64)f2bf(centroids[i])     << (16 * i);
    #pragma unroll
    for (int i = 0; i < 4; i++) lut1 |= (u64)f2bf(centroids[4 + i]) << (16 * i);
}

// Decode 8 consecutive weights at flat position pbase (pbase < 2^24).
__device__ __forceinline__ uint4 decode8(const void* codes, bool i64,
                                         u64 lut0, u64 lut1, unsigned pbase) {
    unsigned q0 = (unsigned)(((u64)pbase * 0xC30C30C4ULL) >> 36);  // pbase/21 exact
    unsigned s0 = pbase - q0 * 21u;
    unsigned q1 = q0 + 1u; if (q1 > (unsigned)(NCODES - 1)) q1 = (unsigned)(NCODES - 1);
    s64 w0, w1;
    if (i64) {
        w0 = ((const s64*)codes)[q0];
        w1 = ((const s64*)codes)[q1];
    } else {
        w0 = (s64)((const int*)codes)[q0];   // sign-extend int32 word
        w1 = (s64)((const int*)codes)[q1];
    }
    unsigned r[4];
    #pragma unroll
    for (int i = 0; i < 8; i++) {
        unsigned s  = s0 + (unsigned)i;
        s64 w       = (s >= 21u) ? w1 : w0;
        unsigned ss = (s >= 21u) ? (s - 21u) : s;
        unsigned idx;
        if (i64) {
            idx = (unsigned)(w >> (3u * ss)) & 7u;
        } else {
            if (ss <= 10u) idx = (unsigned)(w >> (3u * ss)) & 7u;
            else           idx = (w == 0) ? 7u : 6u;   // XLA //0 -> -2 -> %8 = 6
        }
        u64 pk = (idx & 4u) ? lut1 : lut0;
        unsigned val = (unsigned)(pk >> (16u * (idx & 3u))) & 0xFFFFu;
        if (i & 1) r[i >> 1] |= val << 16; else r[i >> 1] = val;
    }
    return make_uint4(r[0], r[1], r[2], r[3]);
}

// ---------------- kernel 1: decode packed codes -> bf16 weight ----------------
__global__ __launch_bounds__(256) void decode_codes_vec(
    const void* __restrict__ codes, const float* __restrict__ centroids,
    uint4* __restrict__ W)
{
    bool i64 = codes_are_i64((const int*)codes);
    u64 lut0, lut1; make_lut(centroids, lut0, lut1);
    unsigned c = blockIdx.x * blockDim.x + threadIdx.x;   // 16B chunk id
    if (c >= NUMEL / 8) return;
    W[c] = decode8(codes, i64, lut0, lut1, c * 8u);
}

// ---------------- kernel 2: X f32 -> bf16, one-shot (8 floats/thread) ----------
__global__ __launch_bounds__(256) void f32_to_bf16_8(
    const float4* __restrict__ x, uint4* __restrict__ y, int n8)
{
    int i = blockIdx.x * blockDim.x + threadIdx.x;
    if (i >= n8) return;
    float4 v0 = x[2 * i], v1 = x[2 * i + 1];
    uint4 o;
    o.x = (unsigned)f2bf(v0.x) | ((unsigned)f2bf(v0.y) << 16);
    o.y = (unsigned)f2bf(v0.z) | ((unsigned)f2bf(v0.w) << 16);
    o.z = (unsigned)f2bf(v1.x) | ((unsigned)f2bf(v1.y) << 16);
    o.w = (unsigned)f2bf(v1.z) | ((unsigned)f2bf(v1.w) << 16);
    y[i] = o;
}

#define GLDS(gaddr, laddr) \
    __builtin_amdgcn_global_load_lds( \
        (const __attribute__((address_space(1))) void*)(gaddr), \
        (__attribute__((address_space(3))) void*)(laddr), 16, 0, 0)

// ---------------- kernel 3: 256x256 bf16 GEMM (B^T) + bias, f32 out ------------
// 512 threads = 8 waves (2M x 4N), per-wave out 128x64 (acc[8][4] 16x16 frags).
// BK=32; LDS 2 slots x (A 256x32 + B 256x32) bf16 = 64KB, double-buffered.
// Counted vmcnt(4) (never 0 in main loop) + raw s_barrier (T3/T4).
// LDS XOR-swizzle: chunk' = chunk ^ ((row>>1)&3)  (16B chunks, 4/row).
//   Stage: linear LDS dest + inverse-swizzled GLOBAL source (rule #21).
//   Read:  swizzled address. 16-lane b128 groups hit each bank-granule 2x (free).
__global__ __launch_bounds__(512, 2) void gemm256(
    const u16* __restrict__ A, const u16* __restrict__ B,
    const float* __restrict__ bias, float* __restrict__ C,
    int M, int N, int K)
{
    __shared__ u16 lds[2 * 16384];   // 64KB

    const int tid  = threadIdx.x;
    const int lane = tid & 63;
    const int wid  = tid >> 6;       // 0..7
    const int wm   = wid >> 2;       // 0..1
    const int wn   = wid & 3;        // 0..3

    // XCD-aware bijective swizzle (gridDim.x = 512, divisible by 8)
    const int cpx = gridDim.x >> 3;
    const int id  = blockIdx.x;
    const int swz = (id & 7) * cpx + (id >> 3);
    const int bx  = swz & 15;        // N-tile (4096/256 = 16)
    const int by  = swz >> 4;        // M-tile
    const int bm  = by * 256;
    const int bn  = bx * 256;

    // staging: 2 A-chunks + 2 B-chunks per thread (chunk = 16B = 8 bf16)
    const u16* gA0; const u16* gA1; const u16* gB0; const u16* gB1;
    int lA0, lA1, lB0, lB1;
    {
        int c0 = tid, c1 = 512 + tid;
        int r0 = c0 >> 2, p0 = c0 & 3, r1 = c1 >> 2, p1 = c1 & 3;
        int g0 = (p0 ^ ((r0 >> 1) & 3)) * 8;   // inverse-swizzled source col
        int g1 = (p1 ^ ((r1 >> 1) & 3)) * 8;
        gA0 = A + (long long)(bm + r0) * K + g0;
        gA1 = A + (long long)(bm + r1) * K + g1;
        gB0 = B + (long long)(bn + r0) * K + g0;
        gB1 = B + (long long)(bn + r1) * K + g1;
        lA0 = c0 * 8; lA1 = c1 * 8;            // linear LDS dest (u16 elems)
        lB0 = 8192 + c0 * 8; lB1 = 8192 + c1 * 8;
    }

    // fragment read offsets (swizzled), u16 elems within a slot
    const int fr = lane & 15;
    const int ck = lane >> 4;        // 16B col-chunk 0..3
    int offA[8], offB[4];
    #pragma unroll
    for (int m = 0; m < 8; m++) {
        int r = wm * 128 + m * 16 + fr;
        offA[m] = r * 32 + ((ck ^ ((r >> 1) & 3)) * 8);
    }
    #pragma unroll
    for (int n = 0; n < 4; n++) {
        int r = wn * 64 + n * 16 + fr;
        offB[n] = 8192 + r * 32 + ((ck ^ ((r >> 1) & 3)) * 8);
    }

    f32x4 acc[8][4] = {};
    const int nt = K / 32;           // 128 K-tiles

#define STAGE256(t_) do { \
        int sb_ = ((t_) & 1) * 16384; int ko_ = (t_) * 32; \
        GLDS(gA0 + ko_, &lds[sb_ + lA0]); \
        GLDS(gA1 + ko_, &lds[sb_ + lA1]); \
        GLDS(gB0 + ko_, &lds[sb_ + lB0]); \
        GLDS(gB1 + ko_, &lds[sb_ + lB1]); \
    } while (0)

    STAGE256(0);
    for (int t = 0; t < nt; ++t) {
        if (t + 1 < nt) {
            STAGE256(t + 1);                                   // prefetch next tile
            asm volatile("s_waitcnt vmcnt(4)" ::: "memory");   // tile t landed
        } else {
            asm volatile("s_waitcnt vmcnt(0)" ::: "memory");
        }
        __builtin_amdgcn_s_barrier();

        const u16* sl = &lds[(t & 1) * 16384];
        bf16x8 a[8], b[4];
        #pragma unroll
        for (int m = 0; m < 8; m++) a[m] = *(const bf16x8*)&sl[offA[m]];
        #pragma unroll
        for (int n = 0; n < 4; n++) b[n] = *(const bf16x8*)&sl[offB[n]];

        __builtin_amdgcn_s_setprio(1);
        #pragma unroll
        for (int m = 0; m < 8; m++)
            #pragma unroll
            for (int n = 0; n < 4; n++)
                acc[m][n] = __builtin_amdgcn_mfma_f32_16x16x32_bf16(
                    a[m], b[n], acc[m][n], 0, 0, 0);
        __builtin_amdgcn_s_setprio(0);

        asm volatile("s_waitcnt lgkmcnt(0)" ::: "memory");     // reads of slot done
        __builtin_amdgcn_s_barrier();                          // slot reusable
    }

    // Epilogue: D mapping col=lane&15, row=(lane>>4)*4+reg (m89/m91 verified)
    const int cr = (lane >> 4) * 4;
    const int cc = lane & 15;
    #pragma unroll
    for (int m = 0; m < 8; m++) {
        int row = bm + wm * 128 + m * 16 + cr;
        #pragma unroll
        for (int n = 0; n < 4; n++) {
            int col = bn + wn * 64 + n * 16 + cc;
            float bv = bias[col];
            #pragma unroll
            for (int r = 0; r < 4; r++)
                C[(long long)(row + r) * N + col] = acc[m][n][r] + bv;
        }
    }
}

// ---------------- fallback 128x128 GEMM (paths B/C, unchanged from R7) --------
#define BM 128
#define BN 128
#define BK 32

template<bool CONV_A, bool FUSE_B>
__global__ __launch_bounds__(256) void gemm_bt_bias(
    const void* __restrict__ Araw, const void* __restrict__ Braw,
    const float* __restrict__ centroids,
    const float* __restrict__ bias, float* __restrict__ C,
    int M, int N, int K)
{
    __shared__ u16 As[BM * BK];
    __shared__ u16 Bs[BN * BK];

    const int tid  = threadIdx.x;
    const int lane = tid & 63;
    const int wid  = tid >> 6;
    const int wm   = wid >> 1;
    const int wn   = wid & 1;

    const int bm = blockIdx.y * BM;
    const int bn = blockIdx.x * BN;

    bool i64f = false; u64 lut0 = 0, lut1 = 0;
    if constexpr (FUSE_B) {
        i64f = codes_are_i64((const int*)Braw);
        make_lut(centroids, lut0, lut1);
    }

    f32x4 acc[4][4] = {};

    const int r0  = tid >> 2;
    const int cs8 = (tid & 3) * 8;

    const u16* gB0 = nullptr; const u16* gB1 = nullptr;
    if constexpr (!FUSE_B) {
        const u16* Bb = (const u16*)Braw;
        gB0 = Bb + (long long)(bn + r0)      * K + cs8;
        gB1 = Bb + (long long)(bn + r0 + 64) * K + cs8;
    }
    const u16* gA0 = nullptr; const u16* gA1 = nullptr;
    const float* fA0 = nullptr; const float* fA1 = nullptr;
    if constexpr (CONV_A) {
        const float* Af = (const float*)Araw;
        fA0 = Af + (long long)(bm + r0)      * K + cs8;
        fA1 = Af + (long long)(bm + r0 + 64) * K + cs8;
    } else {
        const u16* Ab = (const u16*)Araw;
        gA0 = Ab + (long long)(bm + r0)      * K + cs8;
        gA1 = Ab + (long long)(bm + r0 + 64) * K + cs8;
    }

    const int fr = lane & 15;
    const int fk = (lane >> 4) * 8;

    for (int kt = 0; kt < K; kt += BK) {
        if constexpr (FUSE_B) {
            uint4 b0 = decode8(Braw, i64f, lut0, lut1,
                               (unsigned)((bn + r0) * K + kt + cs8));
            uint4 b1 = decode8(Braw, i64f, lut0, lut1,
                               (unsigned)((bn + r0 + 64) * K + kt + cs8));
            *(uint4*)&Bs[tid * 8]        = b0;
            *(uint4*)&Bs[2048 + tid * 8] = b1;
        } else {
            GLDS(gB0 + kt, &Bs[tid * 8]);
            GLDS(gB1 + kt, &Bs[2048 + tid * 8]);
        }
        if constexpr (CONV_A) {
            f32x4 v0 = *(const f32x4*)(fA0 + kt);
            f32x4 v1 = *(const f32x4*)(fA0 + kt + 4);
            f32x4 v2 = *(const f32x4*)(fA1 + kt);
            f32x4 v3 = *(const f32x4*)(fA1 + kt + 4);
            bf16x8 a0, a1;
            #pragma unroll
            for (int i = 0; i < 4; i++) {
                a0[i]     = (__bf16)v0[i];
                a0[i + 4] = (__bf16)v1[i];
                a1[i]     = (__bf16)v2[i];
                a1[i + 4] = (__bf16)v3[i];
            }
            *(bf16x8*)&As[tid * 8]        = a0;
            *(bf16x8*)&As[2048 + tid * 8] = a1;
        } else {
            GLDS(gA0 + kt, &As[tid * 8]);
            GLDS(gA1 + kt, &As[2048 + tid * 8]);
        }
        __syncthreads();

        bf16x8 a[4], b[4];
        #pragma unroll
        for (int i = 0; i < 4; i++) {
            a[i] = *(const bf16x8*)&As[(wm * 64 + i * 16 + fr) * BK + fk];
            b[i] = *(const bf16x8*)&Bs[(wn * 64 + i * 16 + fr) * BK + fk];
        }
        #pragma unroll
        for (int i = 0; i < 4; i++)
            #pragma unroll
            for (int j = 0; j < 4; j++)
                acc[i][j] = __builtin_amdgcn_mfma_f32_16x16x32_bf16(
                    a[i], b[j], acc[i][j], 0, 0, 0);
        __syncthreads();
    }

    const int cr = (lane >> 4) * 4;
    const int cc = lane & 15;
    #pragma unroll
    for (int i = 0; i < 4; i++) {
        int row = bm + wm * 64 + i * 16 + cr;
        #pragma unroll
        for (int j = 0; j < 4; j++) {
            int col = bn + wn * 64 + j * 16 + cc;
            float bv = bias[col];
            #pragma unroll
            for (int r = 0; r < 4; r++) {
                C[(long long)(row + r) * N + col] = acc[i][j][r] + bv;
            }
        }
    }
}

extern "C" void kernel_launch(void* const* d_in, const int* in_sizes, int n_in,
                              void* d_out, int out_size, void* d_ws, size_t ws_size,
                              hipStream_t stream) {
    const float* input_    = (const float*)d_in[0];   // [4,2048,4096] f32
    const void*  codes     = d_in[1];                 // [798916] i32 (probed)
    const float* centroids = (const float*)d_in[2];   // [8] f32
    const float* bias      = (const float*)d_in[3];   // [4096] f32
    float*       out       = (float*)d_out;           // [8192,4096] f32

    const int M = in_sizes[0] / IN_DIM;               // 8192

    const size_t needW = (size_t)NUMEL * 2;           // 33.5 MB
    const size_t needX = (size_t)M * IN_DIM * 2;      // 67 MB

    if (ws_size >= needW + needX) {
        // Path A (R7-confirmed active): decode W + convert X + 256^2 pipelined GEMM
        u16* W = (u16*)d_ws;
        u16* X = (u16*)((char*)d_ws + needW);
        decode_codes_vec<<<(NUMEL / 8) / 256, 256, 0, stream>>>(codes, centroids, (uint4*)W);
        int n8 = (M * IN_DIM) / 8;
        f32_to_bf16_8<<<n8 / 256, 256, 0, stream>>>((const float4*)input_, (uint4*)X, n8);
        int nblk = (M / 256) * (OUT_DIM / 256);       // 32*16 = 512
        gemm256<<<nblk, 512, 0, stream>>>(X, W, bias, out, M, OUT_DIM, IN_DIM);
    } else if (ws_size >= needW) {
        // Path B: decode W; 128^2 GEMM converts f32 A on the fly
        u16* W = (u16*)d_ws;
        decode_codes_vec<<<(NUMEL / 8) / 256, 256, 0, stream>>>(codes, centroids, (uint4*)W);
        dim3 grid(OUT_DIM / BN, M / BM);
        gemm_bt_bias<true, false><<<grid, 256, 0, stream>>>(
            input_, W, centroids, bias, out, M, OUT_DIM, IN_DIM);
    } else {
        // Path C: zero-scratch fused
        dim3 grid(OUT_DIM / BN, M / BM);
        gemm_bt_bias<true, true><<<grid, 256, 0, stream>>>(
            input_, codes, centroids, bias, out, M, OUT_DIM, IN_DIM);
    }
}